// Round 10
// baseline (880.618 us; speedup 1.0000x reference)
//
#include <hip/hip_runtime.h>

// ICNN forward-of-gradient: out = 0.5*d(scalar)/dx + 0.5*x
// R2: all GEMMs on bf16 MFMA (16x16x32) with hi/lo split (3-product ~ fp32 accuracy).
// R3: fusion round — u stored in forward, bwd_g+bwd_x merged, final fused, prep fused.
// R5: uniform bwd blocks; a1=2u*ga in g-epilogue (in-place over uL).
// R7-R11: schedule/occupancy/swizzle/tile sweeps ALL flat at ~50us/dispatch.
//     Invariant: hbm_bytes ~105MB @ 2.1TB/s; epilogue = 112 scalar 2B mem-ops/thread.
// R12: kill the a1 round-trip — x-path computes a1=2*u*ga on the fly (reg-staged
//     pass-0 A with ds_write_b128), g-epilogue only writes ga (48 ops/thread),
//     -33.6MB HBM/dispatch. ga_init simplified. Main loops unchanged from R11.

#define Bn 8192
#define Dn 128
#define Hn 512
#define Ln 10

constexpr float NS = 0.2f;

typedef __attribute__((ext_vector_type(8))) short short8;   // 8 bf16 = 4 VGPRs (A/B frag)
typedef __attribute__((ext_vector_type(4))) float f32x4;    // C/D frag

typedef const __attribute__((address_space(1))) void GV;
typedef __attribute__((address_space(3))) void LV;

__device__ __forceinline__ void gload16(const void* g, void* l) {
    __builtin_amdgcn_global_load_lds((GV*)g, (LV*)l, 16, 0, 0);
}

#define MFMA(acc, a, b) acc = __builtin_amdgcn_mfma_f32_16x16x32_bf16(a, b, acc, 0, 0, 0)

__device__ __forceinline__ unsigned short bf16_rne(float v) {
    unsigned u = __float_as_uint(v);
    u += 0x7FFFu + ((u >> 16) & 1u);
    return (unsigned short)(u >> 16);
}
__device__ __forceinline__ float bf2f(unsigned short h) {
    return __uint_as_float(((unsigned)h) << 16);
}
__device__ __forceinline__ void split2(float v, unsigned short& h, unsigned short& l) {
    h = bf16_rne(v);
    l = bf16_rne(v - bf2f(h));
}

// ---------------- prep kernels ----------------

__global__ __launch_bounds__(256) void split_flat(const float* __restrict__ in,
        unsigned short* __restrict__ hi, unsigned short* __restrict__ lo, int n4) {
    int i = blockIdx.x * 256 + threadIdx.x;
    if (i >= n4) return;
    float4 v = ((const float4*)in)[i];
    ushort4 h, l;
    split2(v.x, h.x, l.x);
    split2(v.y, h.y, l.y);
    split2(v.z, h.z, l.z);
    split2(v.w, h.w, l.w);
    ((ushort4*)hi)[i] = h;
    ((ushort4*)lo)[i] = l;
}

// per-layer: in [R,C] fp32 -> straight split [R,C] hi/lo AND transposed split [C,R] hi/lo
__global__ __launch_bounds__(256) void split_both(const float* __restrict__ in,
        unsigned short* __restrict__ hi, unsigned short* __restrict__ lo,
        unsigned short* __restrict__ thi, unsigned short* __restrict__ tlo,
        int R, int C) {
    __shared__ float t[32][33];
    const size_t off = (size_t)blockIdx.z * R * C;
    const float* src = in + off;
    unsigned short* sh_ = hi + off;
    unsigned short* sl_ = lo + off;
    unsigned short* dh = thi + off;
    unsigned short* dl = tlo + off;
    const int r0 = blockIdx.x * 32, c0 = blockIdx.y * 32;
    const int tr = threadIdx.x >> 5, tc = threadIdx.x & 31;
#pragma unroll
    for (int i = 0; i < 4; ++i) {
        size_t si = (size_t)(r0 + tr + 8 * i) * C + c0 + tc;
        float v = src[si];
        t[tr + 8 * i][tc] = v;
        unsigned short h, l; split2(v, h, l);
        sh_[si] = h; sl_[si] = l;
    }
    __syncthreads();
#pragma unroll
    for (int i = 0; i < 4; ++i) {
        float v = t[tc][tr + 8 * i];
        unsigned short h, l; split2(v, h, l);
        size_t o = (size_t)(c0 + tr + 8 * i) * R + r0 + tc;
        dh[o] = h; dl[o] = l;
    }
}

// ---------------- fwd layer: 128x64 tile, NT, 3-product split (unchanged, known-good) ----------------

__global__ __launch_bounds__(256) void fwd_mfma(
    const unsigned short* __restrict__ xh, const unsigned short* __restrict__ xl,
    const unsigned short* __restrict__ zph, const unsigned short* __restrict__ zpl,
    const unsigned short* __restrict__ Wzh, const unsigned short* __restrict__ Wzl,
    const unsigned short* __restrict__ Wqh, const unsigned short* __restrict__ Wql,
    const unsigned short* __restrict__ Wlh, const unsigned short* __restrict__ Wll,
    const float* __restrict__ bl,
    unsigned short* __restrict__ zoh, unsigned short* __restrict__ zol,
    unsigned short* __restrict__ mask16,
    unsigned short* __restrict__ uoh, unsigned short* __restrict__ uol, int hasZ)
{
    __shared__ __align__(16) char smem[32768];
    unsigned short* Ah  = (unsigned short*)smem;            // [128][32]
    unsigned short* Al  = (unsigned short*)(smem + 8192);
    unsigned short* B0h = (unsigned short*)(smem + 16384);  // [64][32]
    unsigned short* B0l = (unsigned short*)(smem + 20480);
    unsigned short* B1h = (unsigned short*)(smem + 24576);
    unsigned short* B1l = (unsigned short*)(smem + 28672);

    const int tid = threadIdx.x;
    const int w = tid >> 6, lane = tid & 63;
    const int lq = lane >> 4, lc = lane & 15;
    const int wm = (w & 1) * 64, wn = (w >> 1) * 32;
    const int row0 = blockIdx.x * 128, col0 = blockIdx.y * 64;
    const int sr = lane >> 2, sk = (lane & 3) * 8;

    f32x4 accz[4][2], accu[4][2], accv[4][2];
#pragma unroll
    for (int i = 0; i < 4; ++i)
#pragma unroll
        for (int j = 0; j < 2; ++j)
#pragma unroll
            for (int r = 0; r < 4; ++r) { accz[i][j][r] = 0.f; accu[i][j][r] = 0.f; accv[i][j][r] = 0.f; }

    if (hasZ) {
        for (int k0 = 0; k0 < Hn; k0 += 32) {
            __syncthreads();
            for (int c = w; c < 8; c += 4) {
                size_t go = (size_t)(row0 + c * 16 + sr) * Hn + k0 + sk;
                gload16(zph + go, Ah + c * 512);
                gload16(zpl + go, Al + c * 512);
            }
            {
                int c = w;
                size_t go = (size_t)(col0 + c * 16 + sr) * Hn + k0 + sk;
                gload16(Wzh + go, B0h + c * 512);
                gload16(Wzl + go, B0l + c * 512);
            }
            __syncthreads();
            short8 ah[4], al[4];
#pragma unroll
            for (int mt = 0; mt < 4; ++mt) {
                int ao = (wm + mt * 16 + lc) * 32 + lq * 8;
                ah[mt] = *(const short8*)(Ah + ao);
                al[mt] = *(const short8*)(Al + ao);
            }
#pragma unroll
            for (int nt = 0; nt < 2; ++nt) {
                int bo = (wn + nt * 16 + lc) * 32 + lq * 8;
                short8 bh = *(const short8*)(B0h + bo);
                short8 bv = *(const short8*)(B0l + bo);
#pragma unroll
                for (int mt = 0; mt < 4; ++mt) {
                    MFMA(accz[mt][nt], ah[mt], bh);
                    MFMA(accz[mt][nt], ah[mt], bv);
                    MFMA(accz[mt][nt], al[mt], bh);
                }
            }
        }
    }

    for (int k0 = 0; k0 < Dn; k0 += 32) {
        __syncthreads();
        for (int c = w; c < 8; c += 4) {
            size_t go = (size_t)(row0 + c * 16 + sr) * Dn + k0 + sk;
            gload16(xh + go, Ah + c * 512);
            gload16(xl + go, Al + c * 512);
        }
        {
            int c = w;
            size_t go = (size_t)(col0 + c * 16 + sr) * Dn + k0 + sk;
            gload16(Wqh + go, B0h + c * 512);
            gload16(Wql + go, B0l + c * 512);
            gload16(Wlh + go, B1h + c * 512);
            gload16(Wll + go, B1l + c * 512);
        }
        __syncthreads();
        short8 ah[4], al[4];
#pragma unroll
        for (int mt = 0; mt < 4; ++mt) {
            int ao = (wm + mt * 16 + lc) * 32 + lq * 8;
            ah[mt] = *(const short8*)(Ah + ao);
            al[mt] = *(const short8*)(Al + ao);
        }
#pragma unroll
        for (int nt = 0; nt < 2; ++nt) {
            int bo = (wn + nt * 16 + lc) * 32 + lq * 8;
            short8 bqh = *(const short8*)(B0h + bo);
            short8 bql = *(const short8*)(B0l + bo);
            short8 blh = *(const short8*)(B1h + bo);
            short8 bll = *(const short8*)(B1l + bo);
#pragma unroll
            for (int mt = 0; mt < 4; ++mt) {
                MFMA(accu[mt][nt], ah[mt], bqh);
                MFMA(accu[mt][nt], ah[mt], bql);
                MFMA(accu[mt][nt], al[mt], bqh);
                MFMA(accv[mt][nt], ah[mt], blh);
                MFMA(accv[mt][nt], ah[mt], bll);
                MFMA(accv[mt][nt], al[mt], blh);
            }
        }
    }

#pragma unroll
    for (int nt = 0; nt < 2; ++nt) {
        const int colb = col0 + wn + nt * 16;
        const int col = colb + lc;
        const float blv = bl[col];
#pragma unroll
        for (int mt = 0; mt < 4; ++mt) {
            const int rowb = row0 + wm + mt * 16;
#pragma unroll
            for (int r = 0; r < 4; ++r) {
                float uq = accu[mt][nt][r];
                float pre = accz[mt][nt][r] + uq * uq + accv[mt][nt][r] + blv;
                bool m = pre >= 0.f;
                unsigned long long bal = __ballot(m);
                if (lc == 0) {
                    int rw = rowb + lq * 4 + r;
                    mask16[(size_t)rw * 32 + (colb >> 4)] =
                        (unsigned short)((bal >> (lq * 16)) & 0xFFFFull);
                }
                float zv = m ? pre : NS * pre;
                unsigned short h, l; split2(zv, h, l);
                size_t o = (size_t)(rowb + lq * 4 + r) * Hn + col;
                zoh[o] = h; zol[o] = l;
                unsigned short uhh, ull; split2(uq, uhh, ull);
                uoh[o] = uhh; uol[o] = ull;
            }
        }
    }
}

// ---------------- merged backward layer kernel (R11 structure, a1 on the fly) ----------------
// blocks [0, nG=1024): ga_{l-1} = (ga_l @ Wz) o mask'  (64x64 tiles, grid 128x8).
//                      Epilogue writes ONLY ga (u/a1 round-trip deleted).
// blocks [nG, nG+256): gx = (2*u_l o ga_l)@WqT' + ga_l@WlT'  (64x64, 32-iter merged
//                      passes; pass 0 A = a1 computed on the fly, reg-staged).
// finalF: fuse out = 0.5*(gx+acc) + s*wq_out + 0.5*wl_out + 0.5*x

__global__ __launch_bounds__(256) void bwd_combo(
    const unsigned short* __restrict__ gah, const unsigned short* __restrict__ gal,
    const unsigned short* __restrict__ WzTh, const unsigned short* __restrict__ WzTl,
    const unsigned short* __restrict__ maskprev,
    unsigned short* __restrict__ goh, unsigned short* __restrict__ gol,
    const unsigned short* __restrict__ uh_, const unsigned short* __restrict__ ul_,
    const unsigned short* __restrict__ WqTh, const unsigned short* __restrict__ WqTl,
    const unsigned short* __restrict__ WlTh, const unsigned short* __restrict__ WlTl,
    float* __restrict__ gx, int addTo, int nG, int finalF,
    const float* __restrict__ xin, const float* __restrict__ s,
    const float* __restrict__ wq_out, const float* __restrict__ wl_out)
{
    __shared__ __align__(16) char smem[16384];
    unsigned short* Ah = (unsigned short*)smem;             // [64][32]
    unsigned short* Al = (unsigned short*)(smem + 4096);
    unsigned short* Bh = (unsigned short*)(smem + 8192);    // [64][32]
    unsigned short* Bl = (unsigned short*)(smem + 12288);

    const int bid = blockIdx.x;
    const int tid = threadIdx.x;
    const int w = tid >> 6, lane = tid & 63;
    const int lq = lane >> 4, lc = lane & 15;
    const int sr = lane >> 2, sk = (lane & 3) * 8;
    const int wm = (w & 1) * 32, wn = (w >> 1) * 32;

    f32x4 acc[2][2];
#pragma unroll
    for (int i = 0; i < 2; ++i)
#pragma unroll
        for (int j = 0; j < 2; ++j)
#pragma unroll
            for (int r = 0; r < 4; ++r) acc[i][j][r] = 0.f;

    if (bid < nG) {
        // ---------- g path: 64x64 tile (grid 128 row-blocks x 8 col-blocks) ----------
        const int row0 = (bid & 127) * 64, col0 = (bid >> 7) * 64;

        for (int k0 = 0; k0 < Hn; k0 += 32) {
            __syncthreads();
            {
                size_t ga_ = (size_t)(row0 + w * 16 + sr) * Hn + k0 + sk;
                gload16(gah + ga_, Ah + w * 512);
                gload16(gal + ga_, Al + w * 512);
                size_t gb_ = (size_t)(col0 + w * 16 + sr) * Hn + k0 + sk;
                gload16(WzTh + gb_, Bh + w * 512);
                gload16(WzTl + gb_, Bl + w * 512);
            }
            __syncthreads();
            short8 ah[2], al[2];
#pragma unroll
            for (int mt = 0; mt < 2; ++mt) {
                int ao = (wm + mt * 16 + lc) * 32 + lq * 8;
                ah[mt] = *(const short8*)(Ah + ao);
                al[mt] = *(const short8*)(Al + ao);
            }
#pragma unroll
            for (int nt = 0; nt < 2; ++nt) {
                int bo = (wn + nt * 16 + lc) * 32 + lq * 8;
                short8 bh = *(const short8*)(Bh + bo);
                short8 bv = *(const short8*)(Bl + bo);
#pragma unroll
                for (int mt = 0; mt < 2; ++mt) {
                    MFMA(acc[mt][nt], ah[mt], bh);
                    MFMA(acc[mt][nt], ah[mt], bv);
                    MFMA(acc[mt][nt], al[mt], bh);
                }
            }
        }

#pragma unroll
        for (int nt = 0; nt < 2; ++nt) {
            const int colb = col0 + wn + nt * 16;
            const int col = colb + lc;
#pragma unroll
            for (int mt = 0; mt < 2; ++mt) {
                const int rowb = row0 + wm + mt * 16;
#pragma unroll
                for (int r = 0; r < 4; ++r) {
                    int row = rowb + lq * 4 + r;
                    unsigned short wbits = maskprev[(size_t)row * 32 + (colb >> 4)];
                    float f = ((wbits >> lc) & 1) ? 1.f : NS;
                    float v = acc[mt][nt][r] * f;
                    unsigned short h, l; split2(v, h, l);
                    size_t o = (size_t)row * Hn + col;
                    goh[o] = h; gol[o] = l;
                }
            }
        }
    } else {
        // ---------- x path: 64x64 tile, 32-iter merged passes; pass0 A = a1 on the fly ----------
        const int t = bid - nG;
        const int row0 = (t >> 1) * 64, col0 = (t & 1) * 64;

        for (int j = 0; j < 32; ++j) {
            const int pass = j >> 4, k0 = (j & 15) * 32;
            __syncthreads();
            if (pass == 0) {
                // A-tile = a1 = 2*u*ga computed in registers, written wide to LDS.
                size_t ga_ = (size_t)(row0 + w * 16 + sr) * Hn + k0 + sk;
                ushort4 gh0 = *(const ushort4*)(gah + ga_);
                ushort4 gh1 = *(const ushort4*)(gah + ga_ + 4);
                ushort4 gl0 = *(const ushort4*)(gal + ga_);
                ushort4 gl1 = *(const ushort4*)(gal + ga_ + 4);
                ushort4 vh0 = *(const ushort4*)(uh_ + ga_);
                ushort4 vh1 = *(const ushort4*)(uh_ + ga_ + 4);
                ushort4 vl0 = *(const ushort4*)(ul_ + ga_);
                ushort4 vl1 = *(const ushort4*)(ul_ + ga_ + 4);
                ushort4 oh0, oh1, ol0, ol1;
                float g, u, a;
                g = bf2f(gh0.x) + bf2f(gl0.x); u = bf2f(vh0.x) + bf2f(vl0.x);
                a = 2.f * u * g; split2(a, oh0.x, ol0.x);
                g = bf2f(gh0.y) + bf2f(gl0.y); u = bf2f(vh0.y) + bf2f(vl0.y);
                a = 2.f * u * g; split2(a, oh0.y, ol0.y);
                g = bf2f(gh0.z) + bf2f(gl0.z); u = bf2f(vh0.z) + bf2f(vl0.z);
                a = 2.f * u * g; split2(a, oh0.z, ol0.z);
                g = bf2f(gh0.w) + bf2f(gl0.w); u = bf2f(vh0.w) + bf2f(vl0.w);
                a = 2.f * u * g; split2(a, oh0.w, ol0.w);
                g = bf2f(gh1.x) + bf2f(gl1.x); u = bf2f(vh1.x) + bf2f(vl1.x);
                a = 2.f * u * g; split2(a, oh1.x, ol1.x);
                g = bf2f(gh1.y) + bf2f(gl1.y); u = bf2f(vh1.y) + bf2f(vl1.y);
                a = 2.f * u * g; split2(a, oh1.y, ol1.y);
                g = bf2f(gh1.z) + bf2f(gl1.z); u = bf2f(vh1.z) + bf2f(vl1.z);
                a = 2.f * u * g; split2(a, oh1.z, ol1.z);
                g = bf2f(gh1.w) + bf2f(gl1.w); u = bf2f(vh1.w) + bf2f(vl1.w);
                a = 2.f * u * g; split2(a, oh1.w, ol1.w);
                int lo_ = (w * 16 + sr) * 32 + sk;
                *(ushort4*)(Ah + lo_) = oh0; *(ushort4*)(Ah + lo_ + 4) = oh1;
                *(ushort4*)(Al + lo_) = ol0; *(ushort4*)(Al + lo_ + 4) = ol1;
                size_t gb_ = (size_t)(col0 + w * 16 + sr) * Hn + k0 + sk;
                gload16(WqTh + gb_, Bh + w * 512);
                gload16(WqTl + gb_, Bl + w * 512);
            } else {
                size_t ga_ = (size_t)(row0 + w * 16 + sr) * Hn + k0 + sk;
                gload16(gah + ga_, Ah + w * 512);
                gload16(gal + ga_, Al + w * 512);
                size_t gb_ = (size_t)(col0 + w * 16 + sr) * Hn + k0 + sk;
                gload16(WlTh + gb_, Bh + w * 512);
                gload16(WlTl + gb_, Bl + w * 512);
            }
            __syncthreads();
            short8 ah[2], al[2];
#pragma unroll
            for (int mt = 0; mt < 2; ++mt) {
                int ao = (wm + mt * 16 + lc) * 32 + lq * 8;
                ah[mt] = *(const short8*)(Ah + ao);
                al[mt] = *(const short8*)(Al + ao);
            }
#pragma unroll
            for (int nt = 0; nt < 2; ++nt) {
                int bo = (wn + nt * 16 + lc) * 32 + lq * 8;
                short8 bh = *(const short8*)(Bh + bo);
                short8 bv = *(const short8*)(Bl + bo);
#pragma unroll
                for (int mt = 0; mt < 2; ++mt) {
                    MFMA(acc[mt][nt], ah[mt], bh);
                    MFMA(acc[mt][nt], ah[mt], bv);
                    MFMA(acc[mt][nt], al[mt], bh);
                }
            }
        }

#pragma unroll
        for (int nt = 0; nt < 2; ++nt) {
            const int col = col0 + wn + nt * 16 + lc;
#pragma unroll
            for (int mt = 0; mt < 2; ++mt) {
                const int rowb = row0 + wm + mt * 16;
#pragma unroll
                for (int r = 0; r < 4; ++r) {
                    const int row = rowb + lq * 4 + r;
                    size_t o = (size_t)row * Dn + col;
                    float v = acc[mt][nt][r];
                    if (addTo) v += gx[o];
                    if (finalF) {
                        v = 0.5f * v + s[row] * wq_out[col] + 0.5f * wl_out[col]
                            + 0.5f * xin[o];
                    }
                    gx[o] = v;
                }
            }
        }
    }
}

// ---------------- small kernels ----------------

// ga_9 = wz_out o mask' (a1 no longer materialized).
__global__ __launch_bounds__(256) void ga_init(
    const float* __restrict__ wz_out, const unsigned short* __restrict__ mask9,
    unsigned short* __restrict__ gh, unsigned short* __restrict__ gl)
{
    int i = blockIdx.x * 256 + threadIdx.x;
    int e = i << 2;
    int b = e >> 9, h = e & 511;
    unsigned short wbits = mask9[(size_t)b * 32 + (h >> 4)];
    float4 wv = *(const float4*)(wz_out + h);
    int sh = h & 15;
    ushort4 oh, ol;
    float f;
    f = wv.x * (((wbits >> (sh + 0)) & 1) ? 1.f : NS); split2(f, oh.x, ol.x);
    f = wv.y * (((wbits >> (sh + 1)) & 1) ? 1.f : NS); split2(f, oh.y, ol.y);
    f = wv.z * (((wbits >> (sh + 2)) & 1) ? 1.f : NS); split2(f, oh.z, ol.z);
    f = wv.w * (((wbits >> (sh + 3)) & 1) ? 1.f : NS); split2(f, oh.w, ol.w);
    *(ushort4*)(gh + e) = oh;
    *(ushort4*)(gl + e) = ol;
}

__global__ __launch_bounds__(256) void rowdot_kernel(
    const float* __restrict__ x, const float* __restrict__ wq_out, float* __restrict__ s) {
    const int b = blockIdx.x * 4 + (threadIdx.x >> 6);
    const int lane = threadIdx.x & 63;
    float v = x[(size_t)b * Dn + lane] * wq_out[lane] +
              x[(size_t)b * Dn + 64 + lane] * wq_out[64 + lane];
#pragma unroll
    for (int off = 32; off > 0; off >>= 1) v += __shfl_down(v, off, 64);
    if (lane == 0) s[b] = v;
}

// ---------------- launcher ----------------

extern "C" void kernel_launch(void* const* d_in, const int* in_sizes, int n_in,
                              void* d_out, int out_size, void* d_ws, size_t ws_size,
                              hipStream_t stream) {
    (void)in_sizes; (void)n_in; (void)out_size; (void)ws_size;
    const float* x      = (const float*)d_in[0];
    const float* Wq     = (const float*)d_in[1];
    const float* Wl     = (const float*)d_in[2];
    const float* bl     = (const float*)d_in[3];
    const float* Wz     = (const float*)d_in[4];
    const float* wz_out = (const float*)d_in[5];
    const float* wq_out = (const float*)d_in[6];
    const float* wl_out = (const float*)d_in[7];
    float* out = (float*)d_out;

    char* p = (char*)d_ws;
    #define CARVE(name, bytes) unsigned short* name = (unsigned short*)p; p += (((size_t)(bytes)) + 255) & ~(size_t)255;
    CARVE(xh,  (size_t)Bn*Dn*2)  CARVE(xl,  (size_t)Bn*Dn*2)
    CARVE(Wqh, (size_t)Ln*Hn*Dn*2) CARVE(Wql, (size_t)Ln*Hn*Dn*2)
    CARVE(Wlh, (size_t)Ln*Hn*Dn*2) CARVE(Wll, (size_t)Ln*Hn*Dn*2)
    CARVE(WqTh,(size_t)Ln*Hn*Dn*2) CARVE(WqTl,(size_t)Ln*Hn*Dn*2)
    CARVE(WlTh,(size_t)Ln*Hn*Dn*2) CARVE(WlTl,(size_t)Ln*Hn*Dn*2)
    CARVE(Wzh, (size_t)(Ln-1)*Hn*Hn*2) CARVE(Wzl, (size_t)(Ln-1)*Hn*Hn*2)
    CARVE(WzTh,(size_t)(Ln-1)*Hn*Hn*2) CARVE(WzTl,(size_t)(Ln-1)*Hn*Hn*2)
    CARVE(zAh, (size_t)Bn*Hn*2) CARVE(zAl, (size_t)Bn*Hn*2)
    CARVE(zBh, (size_t)Bn*Hn*2) CARVE(zBl, (size_t)Bn*Hn*2)
    CARVE(uLh, (size_t)Ln*Bn*Hn*2) CARVE(uLl, (size_t)Ln*Bn*Hn*2)   // u_l bf16 hi/lo (read-only in bwd)
    float* s = (float*)p; p += (size_t)Bn*4;
    unsigned short* mask16 = (unsigned short*)p; p += (size_t)Ln*Bn*32*2;
    #undef CARVE

    // prep: x split + fused weight split/transpose (each weight read once)
    split_flat<<<(Bn*Dn/4 + 255)/256, 256, 0, stream>>>(x, xh, xl, Bn*Dn/4);
    split_both<<<dim3(Hn/32, Dn/32, Ln), 256, 0, stream>>>(Wq, Wqh, Wql, WqTh, WqTl, Hn, Dn);
    split_both<<<dim3(Hn/32, Dn/32, Ln), 256, 0, stream>>>(Wl, Wlh, Wll, WlTh, WlTl, Hn, Dn);
    split_both<<<dim3(Hn/32, Hn/32, Ln-1), 256, 0, stream>>>(Wz, Wzh, Wzl, WzTh, WzTl, Hn, Hn);

    rowdot_kernel<<<Bn/4, 256, 0, stream>>>(x, wq_out, s);

    const dim3 gF(Bn/128, Hn/64);  // 64 x 8

    // forward: z_l hi/lo in (l even ? zA : zB); u_l stored per layer (bf16 hi/lo)
    fwd_mfma<<<gF, 256, 0, stream>>>(xh, xl, nullptr, nullptr, nullptr, nullptr,
        Wqh, Wql, Wlh, Wll, bl, zAh, zAl, mask16, uLh, uLl, 0);
    for (int l = 1; l < Ln; ++l) {
        const unsigned short* zh  = (l & 1) ? zAh : zBh;
        const unsigned short* zl_ = (l & 1) ? zAl : zBl;
        unsigned short* oh  = (l & 1) ? zBh : zAh;
        unsigned short* ol_ = (l & 1) ? zBl : zAl;
        fwd_mfma<<<gF, 256, 0, stream>>>(xh, xl, zh, zl_,
            Wzh + (size_t)(l-1)*Hn*Hn, Wzl + (size_t)(l-1)*Hn*Hn,
            Wqh + (size_t)l*Hn*Dn, Wql + (size_t)l*Hn*Dn,
            Wlh + (size_t)l*Hn*Dn, Wll + (size_t)l*Hn*Dn,
            bl + (size_t)l*Hn, oh, ol_, mask16 + (size_t)l*Bn*32,
            uLh + (size_t)l*Bn*Hn, uLl + (size_t)l*Bn*Hn, 1);
    }

    // backward: ga_9 -> zA slots. Ping-pong downward.
    // l>0: 1024 g-blocks (64x64) + 256 x-blocks = 1280 = 5 blocks/CU. l=0: 256 x-blocks.
    ga_init<<<(Bn*Hn/4)/256, 256, 0, stream>>>(wz_out, mask16 + (size_t)9*Bn*32, zAh, zAl);
    for (int l = Ln - 1; l >= 0; --l) {
        int sidx = (Ln - 1 - l) & 1;
        const unsigned short* gh_  = sidx ? zBh : zAh;
        const unsigned short* gl_  = sidx ? zBl : zAl;
        unsigned short* oh   = sidx ? zAh : zBh;
        unsigned short* ol_  = sidx ? zAl : zBl;
        const int nG = (l > 0) ? 1024 : 0;
        bwd_combo<<<nG + 256, 256, 0, stream>>>(
            gh_, gl_,
            (l > 0) ? WzTh + (size_t)(l-1)*Hn*Hn : nullptr,
            (l > 0) ? WzTl + (size_t)(l-1)*Hn*Hn : nullptr,
            (l > 0) ? mask16 + (size_t)(l-1)*Bn*32 : nullptr,
            (l > 0) ? oh : nullptr, (l > 0) ? ol_ : nullptr,
            uLh + (size_t)l*Bn*Hn, uLl + (size_t)l*Bn*Hn,   // u_l (read-only)
            WqTh + (size_t)l*Dn*Hn, WqTl + (size_t)l*Dn*Hn,
            WlTh + (size_t)l*Dn*Hn, WlTl + (size_t)l*Dn*Hn,
            out, (l == Ln - 1) ? 0 : 1, nG, (l == 0) ? 1 : 0,
            x, s, wq_out, wl_out);
    }
}

// Round 11
// 863.630 us; speedup vs baseline: 1.0197x; 1.0197x over previous
//
#include <hip/hip_runtime.h>

// ICNN forward-of-gradient: out = 0.5*d(scalar)/dx + 0.5*x
// R2: all GEMMs on bf16 MFMA (16x16x32) with hi/lo split (3-product ~ fp32 accuracy).
// R3: fusion round — u stored in forward, bwd_g+bwd_x merged, final fused, prep fused.
// R7-R11: schedule/occupancy/swizzle/tile sweeps ALL flat at ~50us/dispatch.
// R12: a1 on the fly; WRITE -38%, dur flat -> byte volume not the binder.
//     Diagnosis: FETCH 65MB vs 37MB minimal — ga row-panels evicted from 4MB/XCD L2
//     between their 8 col-block uses (row-fast order puts uses ~128 blocks apart);
//     every re-read = ~900cy HBM miss; barrier-locked waves can't hide it.
// R13: T1 XCD-chunked col-fast mapping: xcd=bid%8 owns contiguous row band, col is
//     fastest dim -> panel's 8 uses run back-to-back on one XCD while L2-hot.
//     Applied to bwd g-path, bwd x-path, fwd (1D grid). Index math only.

#define Bn 8192
#define Dn 128
#define Hn 512
#define Ln 10

constexpr float NS = 0.2f;

typedef __attribute__((ext_vector_type(8))) short short8;   // 8 bf16 = 4 VGPRs (A/B frag)
typedef __attribute__((ext_vector_type(4))) float f32x4;    // C/D frag

typedef const __attribute__((address_space(1))) void GV;
typedef __attribute__((address_space(3))) void LV;

__device__ __forceinline__ void gload16(const void* g, void* l) {
    __builtin_amdgcn_global_load_lds((GV*)g, (LV*)l, 16, 0, 0);
}

#define MFMA(acc, a, b) acc = __builtin_amdgcn_mfma_f32_16x16x32_bf16(a, b, acc, 0, 0, 0)

__device__ __forceinline__ unsigned short bf16_rne(float v) {
    unsigned u = __float_as_uint(v);
    u += 0x7FFFu + ((u >> 16) & 1u);
    return (unsigned short)(u >> 16);
}
__device__ __forceinline__ float bf2f(unsigned short h) {
    return __uint_as_float(((unsigned)h) << 16);
}
__device__ __forceinline__ void split2(float v, unsigned short& h, unsigned short& l) {
    h = bf16_rne(v);
    l = bf16_rne(v - bf2f(h));
}

// ---------------- prep kernels ----------------

__global__ __launch_bounds__(256) void split_flat(const float* __restrict__ in,
        unsigned short* __restrict__ hi, unsigned short* __restrict__ lo, int n4) {
    int i = blockIdx.x * 256 + threadIdx.x;
    if (i >= n4) return;
    float4 v = ((const float4*)in)[i];
    ushort4 h, l;
    split2(v.x, h.x, l.x);
    split2(v.y, h.y, l.y);
    split2(v.z, h.z, l.z);
    split2(v.w, h.w, l.w);
    ((ushort4*)hi)[i] = h;
    ((ushort4*)lo)[i] = l;
}

// per-layer: in [R,C] fp32 -> straight split [R,C] hi/lo AND transposed split [C,R] hi/lo
__global__ __launch_bounds__(256) void split_both(const float* __restrict__ in,
        unsigned short* __restrict__ hi, unsigned short* __restrict__ lo,
        unsigned short* __restrict__ thi, unsigned short* __restrict__ tlo,
        int R, int C) {
    __shared__ float t[32][33];
    const size_t off = (size_t)blockIdx.z * R * C;
    const float* src = in + off;
    unsigned short* sh_ = hi + off;
    unsigned short* sl_ = lo + off;
    unsigned short* dh = thi + off;
    unsigned short* dl = tlo + off;
    const int r0 = blockIdx.x * 32, c0 = blockIdx.y * 32;
    const int tr = threadIdx.x >> 5, tc = threadIdx.x & 31;
#pragma unroll
    for (int i = 0; i < 4; ++i) {
        size_t si = (size_t)(r0 + tr + 8 * i) * C + c0 + tc;
        float v = src[si];
        t[tr + 8 * i][tc] = v;
        unsigned short h, l; split2(v, h, l);
        sh_[si] = h; sl_[si] = l;
    }
    __syncthreads();
#pragma unroll
    for (int i = 0; i < 4; ++i) {
        float v = t[tc][tr + 8 * i];
        unsigned short h, l; split2(v, h, l);
        size_t o = (size_t)(c0 + tr + 8 * i) * R + r0 + tc;
        dh[o] = h; dl[o] = l;
    }
}

// ---------------- fwd layer: 128x64 tile, NT, 3-product split ----------------
// 1D grid 512; T1 mapping: xcd=bid%8 owns row-blocks [8*xcd, 8*xcd+8), col fastest.

__global__ __launch_bounds__(256) void fwd_mfma(
    const unsigned short* __restrict__ xh, const unsigned short* __restrict__ xl,
    const unsigned short* __restrict__ zph, const unsigned short* __restrict__ zpl,
    const unsigned short* __restrict__ Wzh, const unsigned short* __restrict__ Wzl,
    const unsigned short* __restrict__ Wqh, const unsigned short* __restrict__ Wql,
    const unsigned short* __restrict__ Wlh, const unsigned short* __restrict__ Wll,
    const float* __restrict__ bl,
    unsigned short* __restrict__ zoh, unsigned short* __restrict__ zol,
    unsigned short* __restrict__ mask16,
    unsigned short* __restrict__ uoh, unsigned short* __restrict__ uol, int hasZ)
{
    __shared__ __align__(16) char smem[32768];
    unsigned short* Ah  = (unsigned short*)smem;            // [128][32]
    unsigned short* Al  = (unsigned short*)(smem + 8192);
    unsigned short* B0h = (unsigned short*)(smem + 16384);  // [64][32]
    unsigned short* B0l = (unsigned short*)(smem + 20480);
    unsigned short* B1h = (unsigned short*)(smem + 24576);
    unsigned short* B1l = (unsigned short*)(smem + 28672);

    const int tid = threadIdx.x;
    const int w = tid >> 6, lane = tid & 63;
    const int lq = lane >> 4, lc = lane & 15;
    const int wm = (w & 1) * 64, wn = (w >> 1) * 32;
    // T1: R=64 row-blocks (128 rows), C=8 col-blocks; col fastest within XCD band.
    const int xcd = blockIdx.x & 7, slot = blockIdx.x >> 3;
    const int row0 = (xcd * 8 + (slot >> 3)) * 128, col0 = (slot & 7) * 64;
    const int sr = lane >> 2, sk = (lane & 3) * 8;

    f32x4 accz[4][2], accu[4][2], accv[4][2];
#pragma unroll
    for (int i = 0; i < 4; ++i)
#pragma unroll
        for (int j = 0; j < 2; ++j)
#pragma unroll
            for (int r = 0; r < 4; ++r) { accz[i][j][r] = 0.f; accu[i][j][r] = 0.f; accv[i][j][r] = 0.f; }

    if (hasZ) {
        for (int k0 = 0; k0 < Hn; k0 += 32) {
            __syncthreads();
            for (int c = w; c < 8; c += 4) {
                size_t go = (size_t)(row0 + c * 16 + sr) * Hn + k0 + sk;
                gload16(zph + go, Ah + c * 512);
                gload16(zpl + go, Al + c * 512);
            }
            {
                int c = w;
                size_t go = (size_t)(col0 + c * 16 + sr) * Hn + k0 + sk;
                gload16(Wzh + go, B0h + c * 512);
                gload16(Wzl + go, B0l + c * 512);
            }
            __syncthreads();
            short8 ah[4], al[4];
#pragma unroll
            for (int mt = 0; mt < 4; ++mt) {
                int ao = (wm + mt * 16 + lc) * 32 + lq * 8;
                ah[mt] = *(const short8*)(Ah + ao);
                al[mt] = *(const short8*)(Al + ao);
            }
#pragma unroll
            for (int nt = 0; nt < 2; ++nt) {
                int bo = (wn + nt * 16 + lc) * 32 + lq * 8;
                short8 bh = *(const short8*)(B0h + bo);
                short8 bv = *(const short8*)(B0l + bo);
#pragma unroll
                for (int mt = 0; mt < 4; ++mt) {
                    MFMA(accz[mt][nt], ah[mt], bh);
                    MFMA(accz[mt][nt], ah[mt], bv);
                    MFMA(accz[mt][nt], al[mt], bh);
                }
            }
        }
    }

    for (int k0 = 0; k0 < Dn; k0 += 32) {
        __syncthreads();
        for (int c = w; c < 8; c += 4) {
            size_t go = (size_t)(row0 + c * 16 + sr) * Dn + k0 + sk;
            gload16(xh + go, Ah + c * 512);
            gload16(xl + go, Al + c * 512);
        }
        {
            int c = w;
            size_t go = (size_t)(col0 + c * 16 + sr) * Dn + k0 + sk;
            gload16(Wqh + go, B0h + c * 512);
            gload16(Wql + go, B0l + c * 512);
            gload16(Wlh + go, B1h + c * 512);
            gload16(Wll + go, B1l + c * 512);
        }
        __syncthreads();
        short8 ah[4], al[4];
#pragma unroll
        for (int mt = 0; mt < 4; ++mt) {
            int ao = (wm + mt * 16 + lc) * 32 + lq * 8;
            ah[mt] = *(const short8*)(Ah + ao);
            al[mt] = *(const short8*)(Al + ao);
        }
#pragma unroll
        for (int nt = 0; nt < 2; ++nt) {
            int bo = (wn + nt * 16 + lc) * 32 + lq * 8;
            short8 bqh = *(const short8*)(B0h + bo);
            short8 bql = *(const short8*)(B0l + bo);
            short8 blh = *(const short8*)(B1h + bo);
            short8 bll = *(const short8*)(B1l + bo);
#pragma unroll
            for (int mt = 0; mt < 4; ++mt) {
                MFMA(accu[mt][nt], ah[mt], bqh);
                MFMA(accu[mt][nt], ah[mt], bql);
                MFMA(accu[mt][nt], al[mt], bqh);
                MFMA(accv[mt][nt], ah[mt], blh);
                MFMA(accv[mt][nt], ah[mt], bll);
                MFMA(accv[mt][nt], al[mt], blh);
            }
        }
    }

#pragma unroll
    for (int nt = 0; nt < 2; ++nt) {
        const int colb = col0 + wn + nt * 16;
        const int col = colb + lc;
        const float blv = bl[col];
#pragma unroll
        for (int mt = 0; mt < 4; ++mt) {
            const int rowb = row0 + wm + mt * 16;
#pragma unroll
            for (int r = 0; r < 4; ++r) {
                float uq = accu[mt][nt][r];
                float pre = accz[mt][nt][r] + uq * uq + accv[mt][nt][r] + blv;
                bool m = pre >= 0.f;
                unsigned long long bal = __ballot(m);
                if (lc == 0) {
                    int rw = rowb + lq * 4 + r;
                    mask16[(size_t)rw * 32 + (colb >> 4)] =
                        (unsigned short)((bal >> (lq * 16)) & 0xFFFFull);
                }
                float zv = m ? pre : NS * pre;
                unsigned short h, l; split2(zv, h, l);
                size_t o = (size_t)(rowb + lq * 4 + r) * Hn + col;
                zoh[o] = h; zol[o] = l;
                unsigned short uhh, ull; split2(uq, uhh, ull);
                uoh[o] = uhh; uol[o] = ull;
            }
        }
    }
}

// ---------------- merged backward layer kernel (R12 structure + T1 mapping) ----------------
// blocks [0, nG=1024): ga_{l-1} = (ga_l @ Wz) o mask'  (64x64 tiles; T1: R=128, C=8,
//                      xcd owns 16 row-blocks, col fastest -> A-panel L2-hot for 8 uses).
// blocks [nG, nG+256): gx = (2*u_l o ga_l)@WqT' + ga_l@WlT'  (64x64, 32-iter merged
//                      passes; pass 0 A = a1 on the fly; T1: R=128, C=2).
// finalF: fuse out = 0.5*(gx+acc) + s*wq_out + 0.5*wl_out + 0.5*x

__global__ __launch_bounds__(256) void bwd_combo(
    const unsigned short* __restrict__ gah, const unsigned short* __restrict__ gal,
    const unsigned short* __restrict__ WzTh, const unsigned short* __restrict__ WzTl,
    const unsigned short* __restrict__ maskprev,
    unsigned short* __restrict__ goh, unsigned short* __restrict__ gol,
    const unsigned short* __restrict__ uh_, const unsigned short* __restrict__ ul_,
    const unsigned short* __restrict__ WqTh, const unsigned short* __restrict__ WqTl,
    const unsigned short* __restrict__ WlTh, const unsigned short* __restrict__ WlTl,
    float* __restrict__ gx, int addTo, int nG, int finalF,
    const float* __restrict__ xin, const float* __restrict__ s,
    const float* __restrict__ wq_out, const float* __restrict__ wl_out)
{
    __shared__ __align__(16) char smem[16384];
    unsigned short* Ah = (unsigned short*)smem;             // [64][32]
    unsigned short* Al = (unsigned short*)(smem + 4096);
    unsigned short* Bh = (unsigned short*)(smem + 8192);    // [64][32]
    unsigned short* Bl = (unsigned short*)(smem + 12288);

    const int bid = blockIdx.x;
    const int tid = threadIdx.x;
    const int w = tid >> 6, lane = tid & 63;
    const int lq = lane >> 4, lc = lane & 15;
    const int sr = lane >> 2, sk = (lane & 3) * 8;
    const int wm = (w & 1) * 32, wn = (w >> 1) * 32;

    f32x4 acc[2][2];
#pragma unroll
    for (int i = 0; i < 2; ++i)
#pragma unroll
        for (int j = 0; j < 2; ++j)
#pragma unroll
            for (int r = 0; r < 4; ++r) acc[i][j][r] = 0.f;

    if (bid < nG) {
        // ---------- g path: 64x64 tile; T1: xcd=bid%8, 16 row-blocks/XCD, col fast ----------
        const int xcd = bid & 7, slot = bid >> 3;           // slot in [0,128)
        const int row0 = (xcd * 16 + (slot >> 3)) * 64, col0 = (slot & 7) * 64;

        for (int k0 = 0; k0 < Hn; k0 += 32) {
            __syncthreads();
            {
                size_t ga_ = (size_t)(row0 + w * 16 + sr) * Hn + k0 + sk;
                gload16(gah + ga_, Ah + w * 512);
                gload16(gal + ga_, Al + w * 512);
                size_t gb_ = (size_t)(col0 + w * 16 + sr) * Hn + k0 + sk;
                gload16(WzTh + gb_, Bh + w * 512);
                gload16(WzTl + gb_, Bl + w * 512);
            }
            __syncthreads();
            short8 ah[2], al[2];
#pragma unroll
            for (int mt = 0; mt < 2; ++mt) {
                int ao = (wm + mt * 16 + lc) * 32 + lq * 8;
                ah[mt] = *(const short8*)(Ah + ao);
                al[mt] = *(const short8*)(Al + ao);
            }
#pragma unroll
            for (int nt = 0; nt < 2; ++nt) {
                int bo = (wn + nt * 16 + lc) * 32 + lq * 8;
                short8 bh = *(const short8*)(Bh + bo);
                short8 bv = *(const short8*)(Bl + bo);
#pragma unroll
                for (int mt = 0; mt < 2; ++mt) {
                    MFMA(acc[mt][nt], ah[mt], bh);
                    MFMA(acc[mt][nt], ah[mt], bv);
                    MFMA(acc[mt][nt], al[mt], bh);
                }
            }
        }

#pragma unroll
        for (int nt = 0; nt < 2; ++nt) {
            const int colb = col0 + wn + nt * 16;
            const int col = colb + lc;
#pragma unroll
            for (int mt = 0; mt < 2; ++mt) {
                const int rowb = row0 + wm + mt * 16;
#pragma unroll
                for (int r = 0; r < 4; ++r) {
                    int row = rowb + lq * 4 + r;
                    unsigned short wbits = maskprev[(size_t)row * 32 + (colb >> 4)];
                    float f = ((wbits >> lc) & 1) ? 1.f : NS;
                    float v = acc[mt][nt][r] * f;
                    unsigned short h, l; split2(v, h, l);
                    size_t o = (size_t)row * Hn + col;
                    goh[o] = h; gol[o] = l;
                }
            }
        }
    } else {
        // ---------- x path: 64x64 tile, 32-iter merged passes; pass0 A = a1 on the fly ----------
        const int t = bid - nG;                             // in [0,256)
        const int xcd = t & 7, slot = t >> 3;               // slot in [0,32)
        const int row0 = (xcd * 16 + (slot >> 1)) * 64, col0 = (slot & 1) * 64;

        for (int j = 0; j < 32; ++j) {
            const int pass = j >> 4, k0 = (j & 15) * 32;
            __syncthreads();
            if (pass == 0) {
                // A-tile = a1 = 2*u*ga computed in registers, written wide to LDS.
                size_t ga_ = (size_t)(row0 + w * 16 + sr) * Hn + k0 + sk;
                ushort4 gh0 = *(const ushort4*)(gah + ga_);
                ushort4 gh1 = *(const ushort4*)(gah + ga_ + 4);
                ushort4 gl0 = *(const ushort4*)(gal + ga_);
                ushort4 gl1 = *(const ushort4*)(gal + ga_ + 4);
                ushort4 vh0 = *(const ushort4*)(uh_ + ga_);
                ushort4 vh1 = *(const ushort4*)(uh_ + ga_ + 4);
                ushort4 vl0 = *(const ushort4*)(ul_ + ga_);
                ushort4 vl1 = *(const ushort4*)(ul_ + ga_ + 4);
                ushort4 oh0, oh1, ol0, ol1;
                float g, u, a;
                g = bf2f(gh0.x) + bf2f(gl0.x); u = bf2f(vh0.x) + bf2f(vl0.x);
                a = 2.f * u * g; split2(a, oh0.x, ol0.x);
                g = bf2f(gh0.y) + bf2f(gl0.y); u = bf2f(vh0.y) + bf2f(vl0.y);
                a = 2.f * u * g; split2(a, oh0.y, ol0.y);
                g = bf2f(gh0.z) + bf2f(gl0.z); u = bf2f(vh0.z) + bf2f(vl0.z);
                a = 2.f * u * g; split2(a, oh0.z, ol0.z);
                g = bf2f(gh0.w) + bf2f(gl0.w); u = bf2f(vh0.w) + bf2f(vl0.w);
                a = 2.f * u * g; split2(a, oh0.w, ol0.w);
                g = bf2f(gh1.x) + bf2f(gl1.x); u = bf2f(vh1.x) + bf2f(vl1.x);
                a = 2.f * u * g; split2(a, oh1.x, ol1.x);
                g = bf2f(gh1.y) + bf2f(gl1.y); u = bf2f(vh1.y) + bf2f(vl1.y);
                a = 2.f * u * g; split2(a, oh1.y, ol1.y);
                g = bf2f(gh1.z) + bf2f(gl1.z); u = bf2f(vh1.z) + bf2f(vl1.z);
                a = 2.f * u * g; split2(a, oh1.z, ol1.z);
                g = bf2f(gh1.w) + bf2f(gl1.w); u = bf2f(vh1.w) + bf2f(vl1.w);
                a = 2.f * u * g; split2(a, oh1.w, ol1.w);
                int lo_ = (w * 16 + sr) * 32 + sk;
                *(ushort4*)(Ah + lo_) = oh0; *(ushort4*)(Ah + lo_ + 4) = oh1;
                *(ushort4*)(Al + lo_) = ol0; *(ushort4*)(Al + lo_ + 4) = ol1;
                size_t gb_ = (size_t)(col0 + w * 16 + sr) * Hn + k0 + sk;
                gload16(WqTh + gb_, Bh + w * 512);
                gload16(WqTl + gb_, Bl + w * 512);
            } else {
                size_t ga_ = (size_t)(row0 + w * 16 + sr) * Hn + k0 + sk;
                gload16(gah + ga_, Ah + w * 512);
                gload16(gal + ga_, Al + w * 512);
                size_t gb_ = (size_t)(col0 + w * 16 + sr) * Hn + k0 + sk;
                gload16(WlTh + gb_, Bh + w * 512);
                gload16(WlTl + gb_, Bl + w * 512);
            }
            __syncthreads();
            short8 ah[2], al[2];
#pragma unroll
            for (int mt = 0; mt < 2; ++mt) {
                int ao = (wm + mt * 16 + lc) * 32 + lq * 8;
                ah[mt] = *(const short8*)(Ah + ao);
                al[mt] = *(const short8*)(Al + ao);
            }
#pragma unroll
            for (int nt = 0; nt < 2; ++nt) {
                int bo = (wn + nt * 16 + lc) * 32 + lq * 8;
                short8 bh = *(const short8*)(Bh + bo);
                short8 bv = *(const short8*)(Bl + bo);
#pragma unroll
                for (int mt = 0; mt < 2; ++mt) {
                    MFMA(acc[mt][nt], ah[mt], bh);
                    MFMA(acc[mt][nt], ah[mt], bv);
                    MFMA(acc[mt][nt], al[mt], bh);
                }
            }
        }

#pragma unroll
        for (int nt = 0; nt < 2; ++nt) {
            const int col = col0 + wn + nt * 16 + lc;
#pragma unroll
            for (int mt = 0; mt < 2; ++mt) {
                const int rowb = row0 + wm + mt * 16;
#pragma unroll
                for (int r = 0; r < 4; ++r) {
                    const int row = rowb + lq * 4 + r;
                    size_t o = (size_t)row * Dn + col;
                    float v = acc[mt][nt][r];
                    if (addTo) v += gx[o];
                    if (finalF) {
                        v = 0.5f * v + s[row] * wq_out[col] + 0.5f * wl_out[col]
                            + 0.5f * xin[o];
                    }
                    gx[o] = v;
                }
            }
        }
    }
}

// ---------------- small kernels ----------------

// ga_9 = wz_out o mask' (a1 no longer materialized).
__global__ __launch_bounds__(256) void ga_init(
    const float* __restrict__ wz_out, const unsigned short* __restrict__ mask9,
    unsigned short* __restrict__ gh, unsigned short* __restrict__ gl)
{
    int i = blockIdx.x * 256 + threadIdx.x;
    int e = i << 2;
    int b = e >> 9, h = e & 511;
    unsigned short wbits = mask9[(size_t)b * 32 + (h >> 4)];
    float4 wv = *(const float4*)(wz_out + h);
    int sh = h & 15;
    ushort4 oh, ol;
    float f;
    f = wv.x * (((wbits >> (sh + 0)) & 1) ? 1.f : NS); split2(f, oh.x, ol.x);
    f = wv.y * (((wbits >> (sh + 1)) & 1) ? 1.f : NS); split2(f, oh.y, ol.y);
    f = wv.z * (((wbits >> (sh + 2)) & 1) ? 1.f : NS); split2(f, oh.z, ol.z);
    f = wv.w * (((wbits >> (sh + 3)) & 1) ? 1.f : NS); split2(f, oh.w, ol.w);
    *(ushort4*)(gh + e) = oh;
    *(ushort4*)(gl + e) = ol;
}

__global__ __launch_bounds__(256) void rowdot_kernel(
    const float* __restrict__ x, const float* __restrict__ wq_out, float* __restrict__ s) {
    const int b = blockIdx.x * 4 + (threadIdx.x >> 6);
    const int lane = threadIdx.x & 63;
    float v = x[(size_t)b * Dn + lane] * wq_out[lane] +
              x[(size_t)b * Dn + 64 + lane] * wq_out[64 + lane];
#pragma unroll
    for (int off = 32; off > 0; off >>= 1) v += __shfl_down(v, off, 64);
    if (lane == 0) s[b] = v;
}

// ---------------- launcher ----------------

extern "C" void kernel_launch(void* const* d_in, const int* in_sizes, int n_in,
                              void* d_out, int out_size, void* d_ws, size_t ws_size,
                              hipStream_t stream) {
    (void)in_sizes; (void)n_in; (void)out_size; (void)ws_size;
    const float* x      = (const float*)d_in[0];
    const float* Wq     = (const float*)d_in[1];
    const float* Wl     = (const float*)d_in[2];
    const float* bl     = (const float*)d_in[3];
    const float* Wz     = (const float*)d_in[4];
    const float* wz_out = (const float*)d_in[5];
    const float* wq_out = (const float*)d_in[6];
    const float* wl_out = (const float*)d_in[7];
    float* out = (float*)d_out;

    char* p = (char*)d_ws;
    #define CARVE(name, bytes) unsigned short* name = (unsigned short*)p; p += (((size_t)(bytes)) + 255) & ~(size_t)255;
    CARVE(xh,  (size_t)Bn*Dn*2)  CARVE(xl,  (size_t)Bn*Dn*2)
    CARVE(Wqh, (size_t)Ln*Hn*Dn*2) CARVE(Wql, (size_t)Ln*Hn*Dn*2)
    CARVE(Wlh, (size_t)Ln*Hn*Dn*2) CARVE(Wll, (size_t)Ln*Hn*Dn*2)
    CARVE(WqTh,(size_t)Ln*Hn*Dn*2) CARVE(WqTl,(size_t)Ln*Hn*Dn*2)
    CARVE(WlTh,(size_t)Ln*Hn*Dn*2) CARVE(WlTl,(size_t)Ln*Hn*Dn*2)
    CARVE(Wzh, (size_t)(Ln-1)*Hn*Hn*2) CARVE(Wzl, (size_t)(Ln-1)*Hn*Hn*2)
    CARVE(WzTh,(size_t)(Ln-1)*Hn*Hn*2) CARVE(WzTl,(size_t)(Ln-1)*Hn*Hn*2)
    CARVE(zAh, (size_t)Bn*Hn*2) CARVE(zAl, (size_t)Bn*Hn*2)
    CARVE(zBh, (size_t)Bn*Hn*2) CARVE(zBl, (size_t)Bn*Hn*2)
    CARVE(uLh, (size_t)Ln*Bn*Hn*2) CARVE(uLl, (size_t)Ln*Bn*Hn*2)   // u_l bf16 hi/lo (read-only in bwd)
    float* s = (float*)p; p += (size_t)Bn*4;
    unsigned short* mask16 = (unsigned short*)p; p += (size_t)Ln*Bn*32*2;
    #undef CARVE

    // prep: x split + fused weight split/transpose (each weight read once)
    split_flat<<<(Bn*Dn/4 + 255)/256, 256, 0, stream>>>(x, xh, xl, Bn*Dn/4);
    split_both<<<dim3(Hn/32, Dn/32, Ln), 256, 0, stream>>>(Wq, Wqh, Wql, WqTh, WqTl, Hn, Dn);
    split_both<<<dim3(Hn/32, Dn/32, Ln), 256, 0, stream>>>(Wl, Wlh, Wll, WlTh, WlTl, Hn, Dn);
    split_both<<<dim3(Hn/32, Hn/32, Ln-1), 256, 0, stream>>>(Wz, Wzh, Wzl, WzTh, WzTl, Hn, Hn);

    rowdot_kernel<<<Bn/4, 256, 0, stream>>>(x, wq_out, s);

    // forward: 1D grid 512 (T1-mapped inside); z_l hi/lo in (l even ? zA : zB)
    fwd_mfma<<<512, 256, 0, stream>>>(xh, xl, nullptr, nullptr, nullptr, nullptr,
        Wqh, Wql, Wlh, Wll, bl, zAh, zAl, mask16, uLh, uLl, 0);
    for (int l = 1; l < Ln; ++l) {
        const unsigned short* zh  = (l & 1) ? zAh : zBh;
        const unsigned short* zl_ = (l & 1) ? zAl : zBl;
        unsigned short* oh  = (l & 1) ? zBh : zAh;
        unsigned short* ol_ = (l & 1) ? zBl : zAl;
        fwd_mfma<<<512, 256, 0, stream>>>(xh, xl, zh, zl_,
            Wzh + (size_t)(l-1)*Hn*Hn, Wzl + (size_t)(l-1)*Hn*Hn,
            Wqh + (size_t)l*Hn*Dn, Wql + (size_t)l*Hn*Dn,
            Wlh + (size_t)l*Hn*Dn, Wll + (size_t)l*Hn*Dn,
            bl + (size_t)l*Hn, oh, ol_, mask16 + (size_t)l*Bn*32,
            uLh + (size_t)l*Bn*Hn, uLl + (size_t)l*Bn*Hn, 1);
    }

    // backward: ga_9 -> zA slots. Ping-pong downward.
    // l>0: 1024 g-blocks (64x64) + 256 x-blocks = 1280 = 5 blocks/CU. l=0: 256 x-blocks.
    ga_init<<<(Bn*Hn/4)/256, 256, 0, stream>>>(wz_out, mask16 + (size_t)9*Bn*32, zAh, zAl);
    for (int l = Ln - 1; l >= 0; --l) {
        int sidx = (Ln - 1 - l) & 1;
        const unsigned short* gh_  = sidx ? zBh : zAh;
        const unsigned short* gl_  = sidx ? zBl : zAl;
        unsigned short* oh   = sidx ? zAh : zBh;
        unsigned short* ol_  = sidx ? zAl : zBl;
        const int nG = (l > 0) ? 1024 : 0;
        bwd_combo<<<nG + 256, 256, 0, stream>>>(
            gh_, gl_,
            (l > 0) ? WzTh + (size_t)(l-1)*Hn*Hn : nullptr,
            (l > 0) ? WzTl + (size_t)(l-1)*Hn*Hn : nullptr,
            (l > 0) ? mask16 + (size_t)(l-1)*Bn*32 : nullptr,
            (l > 0) ? oh : nullptr, (l > 0) ? ol_ : nullptr,
            uLh + (size_t)l*Bn*Hn, uLl + (size_t)l*Bn*Hn,   // u_l (read-only)
            WqTh + (size_t)l*Dn*Hn, WqTl + (size_t)l*Dn*Hn,
            WlTh + (size_t)l*Dn*Hn, WlTl + (size_t)l*Dn*Hn,
            out, (l == Ln - 1) ? 0 : 1, nG, (l == 0) ? 1 : 0,
            x, s, wq_out, wl_out);
    }
}